// Round 6
// baseline (462.457 us; speedup 1.0000x reference)
//
#include <hip/hip_runtime.h>
#include <stdint.h>

#define FDIM 8192
#define KSEL 512
#define NT   512
#define EPT  (FDIM / NT / 4)   // 4 uint4 (16 scalars) per thread per row
#define NBINP 2048             // round-0 bins (11-bit digit, positive side)
#define NWAVE (NT / 64)
#define NBLK 1024              // each block pipelines RPB rows
#define RPB  (FDIM / NBLK)     // 8 rows per block

// Order-preserving float -> uint key (larger key <=> larger float)
__device__ __forceinline__ unsigned keyOf(unsigned u) {
    return (u & 0x80000000u) ? ~u : (u | 0x80000000u);
}
__device__ __forceinline__ float valOf(unsigned key) {
    unsigned u = (key & 0x80000000u) ? (key ^ 0x80000000u) : ~key;
    return __uint_as_float(u);
}

// Barrier draining ONLY LDS/SMEM (lgkmcnt), NOT vmcnt: keeps the next-row
// prefetch loads (and prior-row stores) in flight across radix rounds.
__device__ __forceinline__ void barrier_lgkm() {
    asm volatile("s_waitcnt lgkmcnt(0)" ::: "memory");
    __builtin_amdgcn_s_barrier();
}
// Full drain (rare tie path only): float4 stores must be committed before
// t0's scalar overwrites of threshold-equal slots.
__device__ __forceinline__ void barrier_full() {
    asm volatile("s_waitcnt vmcnt(0) lgkmcnt(0)" ::: "memory");
    __builtin_amdgcn_s_barrier();
}

struct SharedT {
    uint4 hist4[NBINP / 4];                // 8 KiB histogram (self-cleaning scans)
    unsigned wtot[NWAVE];
    unsigned s_prefix, s_need;             // working state (rounds 0-1)
    unsigned s_thresh, s_keepEq, s_eqCnt;  // final results (round-2 only: next
                                           // row's state writes can't clobber
                                           // them mid-store-pass)
    unsigned s_tiecnt;
    unsigned tiebuf[64];
};

__device__ __forceinline__ void process_row(
    const int row, const bool doPrefetch, const int nextRow,
    const float* __restrict__ x, float* __restrict__ out,
    uint4 (&cur)[EPT], uint4 (&nxt)[EPT],
    SharedT& sh, const int t, const int lane, const int wave)
{
    unsigned* hist  = (unsigned*)sh.hist4;
    uint2*    hist2 = (uint2*)sh.hist4;

    // ---- Issue next row's loads FIRST; they stay in flight across all the
    //      lgkm-only barriers below and hide this row's compute tail.
    if (doPrefetch) {
        const uint4* xr = (const uint4*)(x + (size_t)nextRow * FDIM);
        #pragma unroll
        for (int j = 0; j < EPT; ++j) nxt[j] = xr[j * NT + t];
    }
    if (t == 0) sh.s_tiecnt = 0u;   // safe: t0 passed prior row's tie path;
                                    // this row's tie adds are 9 barriers away

    // 2048-bin suffix-scan + straddle; zeroes the bins it reads. Writes
    // s_prefix/s_need; returns grand total of counted keys (block-uniform).
    auto scan2048 = [&](unsigned needP, unsigned prefOr) -> unsigned {
        const uint4 h0 = sh.hist4[t];
        unsigned sfx[5];                    // sfx[i] = sum of own bins [i..3]
        sfx[4] = 0u;
        sfx[3] = h0.w;
        sfx[2] = sfx[3] + h0.z;
        sfx[1] = sfx[2] + h0.y;
        sfx[0] = sfx[1] + h0.x;
        sh.hist4[t] = make_uint4(0u, 0u, 0u, 0u);
        const unsigned tot = sfx[0];
        unsigned incl = tot;                // inclusive suffix over lanes >= this
        #pragma unroll
        for (int off = 1; off < 64; off <<= 1) {
            unsigned y = __shfl_down(incl, off);
            incl += (lane + off < 64) ? y : 0u;
        }
        if (lane == 0) sh.wtot[wave] = incl;
        barrier_lgkm();
        unsigned gb = incl - tot, grand = 0u;
        #pragma unroll
        for (int w = 0; w < NWAVE; ++w) {
            grand += sh.wtot[w];
            gb += (w > wave) ? sh.wtot[w] : 0u;
        }
        const unsigned base = (unsigned)t * 4u;
        #pragma unroll
        for (int i = 0; i < 4; ++i) {
            unsigned S = gb + sfx[i];                  // count with digit >= base+i
            unsigned h = sfx[i] - sfx[i + 1];
            if (S >= needP && S - h < needP) {         // at most one (t,i) hits
                sh.s_prefix = prefOr | (base + (unsigned)i);   // 12-bit prefix
                sh.s_need   = needP - (S - h);
            }
        }
        return grand;
    };

    // ---- Round 0: convert + count chunk-by-chunk as loads land (partial
    //      vmcnt waits per chunk). Positive-side keys only, 11-bit digit.
    {
        unsigned need = KSEL;
        #pragma unroll
        for (int j = 0; j < EPT; ++j) {
            cur[j].x = keyOf(cur[j].x);
            cur[j].y = keyOf(cur[j].y);
            cur[j].z = keyOf(cur[j].z);
            cur[j].w = keyOf(cur[j].w);
            #pragma unroll
            for (int c = 0; c < 4; ++c) {
                unsigned key = (&cur[j].x)[c];
                if (key & 0x80000000u)                 // positive side only
                    atomicAdd(&hist[(key >> 20) & 0x7FFu], 1u);
            }
        }
        barrier_lgkm();
        unsigned grand = scan2048(need, 0x800u);
        barrier_lgkm();
        if (grand < need) {                            // exact fallback (rare)
            need -= grand;                             // all positives are kept
            #pragma unroll
            for (int j = 0; j < EPT; ++j) {
                #pragma unroll
                for (int c = 0; c < 4; ++c) {
                    unsigned key = (&cur[j].x)[c];
                    if (!(key & 0x80000000u))          // negative side
                        atomicAdd(&hist[key >> 20], 1u);
                }
            }
            barrier_lgkm();
            (void)scan2048(need, 0u);
            barrier_lgkm();
        }
    }

    // ---- Rounds 1-2: 10-bit digits over 1024 bins ----
    #pragma unroll
    for (int round = 1; round < 3; ++round) {
        const unsigned pref = sh.s_prefix;   // block-uniform
        const unsigned need = sh.s_need;

        if (round == 1) {
            #pragma unroll
            for (int j = 0; j < EPT; ++j) {
                #pragma unroll
                for (int c = 0; c < 4; ++c) {
                    unsigned key = (&cur[j].x)[c];
                    if ((key >> 20) == pref)                       // ~290 match
                        atomicAdd(&hist[(key >> 10) & 0x3FFu], 1u);
                }
            }
        } else {
            #pragma unroll
            for (int j = 0; j < EPT; ++j) {
                #pragma unroll
                for (int c = 0; c < 4; ++c) {
                    unsigned key = (&cur[j].x)[c];
                    if ((key >> 10) == pref)                       // few match
                        atomicAdd(&hist[key & 0x3FFu], 1u);
                }
            }
        }
        barrier_lgkm();

        // 1024-bin suffix-scan: 2 bins/thread via one ds_read_b64.
        const uint2 h = hist2[t];
        unsigned sfx[3];
        sfx[2] = 0u;
        sfx[1] = h.y;
        sfx[0] = h.y + h.x;
        hist2[t] = make_uint2(0u, 0u);     // self-clean for next round/row
        const unsigned tot = sfx[0];
        unsigned incl = tot;
        #pragma unroll
        for (int off = 1; off < 64; off <<= 1) {
            unsigned y = __shfl_down(incl, off);
            incl += (lane + off < 64) ? y : 0u;
        }
        if (lane == 0) sh.wtot[wave] = incl;
        barrier_lgkm();
        unsigned gb = incl - tot;
        #pragma unroll
        for (int w = 0; w < NWAVE; ++w) gb += (w > wave) ? sh.wtot[w] : 0u;

        const unsigned base = (unsigned)t * 2u;
        #pragma unroll
        for (int i = 0; i < 2; ++i) {
            unsigned S = gb + sfx[i];
            unsigned h2 = sfx[i] - sfx[i + 1];
            if (S >= need && S - h2 < need) {
                if (round == 2) {
                    sh.s_thresh = (pref << 10) | (base + (unsigned)i);
                    sh.s_keepEq = need - (S - h2);
                    sh.s_eqCnt  = h2;
                } else {
                    sh.s_prefix = (pref << 10) | (base + (unsigned)i);
                    sh.s_need   = need - (S - h2);
                }
            }
        }
        barrier_lgkm();
    }

    const unsigned thresh = sh.s_thresh;   // exact key of the KSEL-th largest
    const unsigned keepEq = sh.s_keepEq;   // # threshold-equal elements to keep
    const unsigned eqCnt  = sh.s_eqCnt;    // total threshold-equal elements
    const bool simple = (eqCnt == keepEq);

    float4* orow = (float4*)(out + (size_t)row * FDIM);

    // ---- Output pass straight from registers (coalesced float4 stores) ----
    if (simple) {
        #pragma unroll
        for (int j = 0; j < EPT; ++j) {
            uint4 k = cur[j];
            float4 o;
            o.x = (k.x >= thresh) ? valOf(k.x) : 0.0f;
            o.y = (k.y >= thresh) ? valOf(k.y) : 0.0f;
            o.z = (k.z >= thresh) ? valOf(k.z) : 0.0f;
            o.w = (k.w >= thresh) ? valOf(k.w) : 0.0f;
            orow[j * NT + t] = o;
        }
    } else {
        #pragma unroll
        for (int j = 0; j < EPT; ++j) {
            uint4 k = cur[j];
            float4 o;
            o.x = (k.x > thresh) ? valOf(k.x) : 0.0f;
            o.y = (k.y > thresh) ? valOf(k.y) : 0.0f;
            o.z = (k.z > thresh) ? valOf(k.z) : 0.0f;
            o.w = (k.w > thresh) ? valOf(k.w) : 0.0f;
            orow[j * NT + t] = o;
        }
        // ---- Rare tie path: stable (lowest-index) selection among equals ----
        #pragma unroll
        for (int j = 0; j < EPT; ++j) {
            #pragma unroll
            for (int c = 0; c < 4; ++c) {
                unsigned key = (&cur[j].x)[c];
                if (key == thresh) {
                    unsigned slot = atomicAdd(&sh.s_tiecnt, 1u);
                    if (slot < 64u) sh.tiebuf[slot] = 4u * (unsigned)(j * NT + t) + (unsigned)c;
                }
            }
        }
        barrier_full();   // this row's stores must land before t0's overwrites
        if (t == 0) {
            const unsigned m = sh.s_tiecnt;
            const float v = valOf(thresh);
            if (m <= 64u) {
                for (unsigned i = 0; i < m; ++i) {
                    unsigned idx = sh.tiebuf[i], rank = 0;
                    for (unsigned q = 0; q < m; ++q) rank += (sh.tiebuf[q] < idx);
                    if (rank < keepEq) out[(size_t)row * FDIM + idx] = v;
                }
            } else {
                unsigned c = 0;
                for (int i = 0; i < FDIM && c < keepEq; ++i) {
                    if (keyOf(__float_as_uint(x[(size_t)row * FDIM + i])) == thresh) {
                        out[(size_t)row * FDIM + i] = v; ++c;
                    }
                }
            }
        }
    }
}

// (512, 8): 8 waves/EU min -> 32 waves/CU -> 4 blocks/CU (same residency as
// the 8192-grid version) AND a hard 64-VGPR cap so the kreg double-buffer
// (32 VGPRs) cannot push residency down. R1's (NT,4) mistake requested only
// 2 blocks/CU — that, not the pipelining, caused its regression.
__global__ __launch_bounds__(NT, 8) void topk_mask_kernel(const float* __restrict__ x,
                                                          float* __restrict__ out) {
    __shared__ SharedT sh;

    const int blk  = blockIdx.x;
    const int t    = threadIdx.x;
    const int lane = t & 63;
    const int wave = t >> 6;

    // Prologue: issue row(blk) loads, then zero the histogram under them.
    uint4 rawA[EPT], rawB[EPT];
    {
        const uint4* xr = (const uint4*)(x + (size_t)blk * FDIM);
        #pragma unroll
        for (int j = 0; j < EPT; ++j) rawA[j] = xr[j * NT + t];
    }
    sh.hist4[t] = make_uint4(0u, 0u, 0u, 0u);   // NBINP/4 == NT: one each
    barrier_lgkm();   // zeroes visible before first row's atomics

    // Concurrently-active rows are contiguous (row = r*NBLK + blk): all blocks
    // at pipeline step r stream a contiguous 32 MB slab — good HBM locality.
    #pragma unroll 1
    for (int r = 0; r < RPB; r += 2) {
        process_row(r * NBLK + blk, true, (r + 1) * NBLK + blk,
                    x, out, rawA, rawB, sh, t, lane, wave);
        process_row((r + 1) * NBLK + blk, (r + 2) < RPB,
                    ((r + 2) < RPB ? (r + 2) : 0) * NBLK + blk,
                    x, out, rawB, rawA, sh, t, lane, wave);
    }
}

extern "C" void kernel_launch(void* const* d_in, const int* in_sizes, int n_in,
                              void* d_out, int out_size, void* d_ws, size_t ws_size,
                              hipStream_t stream) {
    const float* x = (const float*)d_in[0];
    float* out = (float*)d_out;
    topk_mask_kernel<<<dim3(NBLK), dim3(NT), 0, stream>>>(x, out);
}

// Round 7
// 432.719 us; speedup vs baseline: 1.0687x; 1.0687x over previous
//
#include <hip/hip_runtime.h>
#include <stdint.h>

#define FDIM 8192
#define KSEL 512
#define NT   512
#define EPT  (FDIM / NT / 4)   // 4 uint4 (16 scalars) per thread
#define NBINP 2048             // round-0 bins (11-bit digit, positive side)
#define NWAVE (NT / 64)

// Order-preserving float -> uint key (larger key <=> larger float)
__device__ __forceinline__ unsigned keyOf(unsigned u) {
    return (u & 0x80000000u) ? ~u : (u | 0x80000000u);
}
__device__ __forceinline__ float valOf(unsigned key) {
    unsigned u = (key & 0x80000000u) ? (key ^ 0x80000000u) : ~key;
    return __uint_as_float(u);
}

// Barrier draining ONLY LDS/SMEM (lgkmcnt), NOT vmcnt: __syncthreads() emits
// s_waitcnt vmcnt(0) before s_barrier, which would serialize the whole row
// load ahead of any counting. Counting chunk j only needs load j (compiler
// emits partial vmcnt waits per use); LDS visibility needs only lgkmcnt(0).
__device__ __forceinline__ void barrier_lgkm() {
    asm volatile("s_waitcnt lgkmcnt(0)" ::: "memory");
    __builtin_amdgcn_s_barrier();
}
// Full drain (rare tie path only): float4 stores must be committed before
// t0's scalar overwrites of threshold-equal slots.
__device__ __forceinline__ void barrier_full() {
    asm volatile("s_waitcnt vmcnt(0) lgkmcnt(0)" ::: "memory");
    __builtin_amdgcn_s_barrier();
}

__global__ __launch_bounds__(NT) void topk_mask_kernel(const float* __restrict__ x,
                                                       float* __restrict__ out) {
    __shared__ uint4 hist4[NBINP / 4];     // 8 KiB histogram
    unsigned* hist  = (unsigned*)hist4;
    uint2*    hist2 = (uint2*)hist4;
    __shared__ unsigned wtot[NWAVE];
    __shared__ unsigned s_prefix, s_need, s_sub, s_tiecnt, s_skip;
    __shared__ unsigned tiebuf[64];

    const int row  = blockIdx.x;
    const int t    = threadIdx.x;
    const int lane = t & 63;
    const int wave = t >> 6;

    const uint4* xrow = (const uint4*)(x + (size_t)row * FDIM);
    float4*      orow = (float4*)(out + (size_t)row * FDIM);

    // ---- Issue ALL row loads first; nothing below drains vmcnt until a
    //      chunk's data is actually consumed.
    uint4 kreg[EPT];
    #pragma unroll
    for (int j = 0; j < EPT; ++j) kreg[j] = xrow[j * NT + t];

    hist4[t] = make_uint4(0u, 0u, 0u, 0u);   // NBINP/4 == NT: one uint4 each
    if (t == 0) { s_tiecnt = 0u; s_skip = 0u; }
    barrier_lgkm();

    // 2048-bin suffix-scan + straddle search; zeroes the bins it reads.
    // Returns the grand total of counted keys (block-uniform).
    auto scan2048 = [&](unsigned needP, unsigned prefOr) -> unsigned {
        const uint4 h0 = hist4[t];
        unsigned sfx[5];                    // sfx[i] = sum of own bins [i..3]
        sfx[4] = 0u;
        sfx[3] = h0.w;
        sfx[2] = sfx[3] + h0.z;
        sfx[1] = sfx[2] + h0.y;
        sfx[0] = sfx[1] + h0.x;
        hist4[t] = make_uint4(0u, 0u, 0u, 0u);   // ready for next phase/round
        const unsigned tot = sfx[0];
        unsigned incl = tot;                // inclusive suffix over lanes >= this
        #pragma unroll
        for (int off = 1; off < 64; off <<= 1) {
            unsigned y = __shfl_down(incl, off);
            incl += (lane + off < 64) ? y : 0u;
        }
        if (lane == 0) wtot[wave] = incl;
        barrier_lgkm();
        unsigned gb = incl - tot, grand = 0u;
        #pragma unroll
        for (int w = 0; w < NWAVE; ++w) {
            grand += wtot[w];
            gb += (w > wave) ? wtot[w] : 0u;
        }
        const unsigned base = (unsigned)t * 4u;
        #pragma unroll
        for (int i = 0; i < 4; ++i) {
            unsigned S = gb + sfx[i];                  // count with digit >= base+i
            unsigned h = sfx[i] - sfx[i + 1];
            if (S >= needP && S - h < needP) {         // at most one (t,i) hits
                s_prefix = prefOr | (base + (unsigned)i);   // 12-bit prefix
                s_need   = needP - (S - h);
                s_sub    = h;
            }
        }
        return grand;
    };

    // ---- Round 0: convert + count chunk-by-chunk as loads land.
    //      Chunk j's atomics depend only on load j -> partial vmcnt waits;
    //      counting overlaps the tail of the load stream.
    {
        unsigned need = KSEL;
        #pragma unroll
        for (int j = 0; j < EPT; ++j) {
            kreg[j].x = keyOf(kreg[j].x);
            kreg[j].y = keyOf(kreg[j].y);
            kreg[j].z = keyOf(kreg[j].z);
            kreg[j].w = keyOf(kreg[j].w);
            #pragma unroll
            for (int c = 0; c < 4; ++c) {
                unsigned key = (&kreg[j].x)[c];
                if (key & 0x80000000u)                 // positive side only
                    atomicAdd(&hist[(key >> 20) & 0x7FFu], 1u);
            }
        }
        barrier_lgkm();
        unsigned grand = scan2048(need, 0x800u);
        barrier_lgkm();
        if (grand < need) {                            // exact fallback (rare)
            need -= grand;                             // all positives are kept
            #pragma unroll
            for (int j = 0; j < EPT; ++j) {
                #pragma unroll
                for (int c = 0; c < 4; ++c) {
                    unsigned key = (&kreg[j].x)[c];
                    if (!(key & 0x80000000u))          // negative side
                        atomicAdd(&hist[key >> 20], 1u);
                }
            }
            barrier_lgkm();
            (void)scan2048(need, 0u);
            barrier_lgkm();
        }
    }

    // ---- Rounds 1-2: 10-bit digits over 1024 bins.
    //      Round-2 skip: if after round 1 the count S of elements with
    //      top-22-bits >= the straddle bin EXACTLY equals `need`, then every
    //      element of the straddle bin is kept, and thresh = bin lower bound
    //      (<<10) with the `>=` output path is already exact. ~75-80% of
    //      N(0,1) rows take this (expected extra occupancy of a 22-bit bin
    //      at the K-th value is ~0.25). Saves a count pass, a scan, and 3
    //      barriers. Block-uniform, bit-exact.
    #pragma unroll
    for (int round = 1; round < 3; ++round) {
        const unsigned pref = s_prefix;   // block-uniform, stable until end-of-round
        const unsigned need = s_need;

        if (round == 2 && s_skip) break;  // read after prior barrier: uniform

        if (round == 1) {
            #pragma unroll
            for (int j = 0; j < EPT; ++j) {
                #pragma unroll
                for (int c = 0; c < 4; ++c) {
                    unsigned key = (&kreg[j].x)[c];
                    if ((key >> 20) == pref)                       // ~290 of 8192 match
                        atomicAdd(&hist[(key >> 10) & 0x3FFu], 1u);
                }
            }
        } else {
            #pragma unroll
            for (int j = 0; j < EPT; ++j) {
                #pragma unroll
                for (int c = 0; c < 4; ++c) {
                    unsigned key = (&kreg[j].x)[c];
                    if ((key >> 10) == pref)                       // few match
                        atomicAdd(&hist[key & 0x3FFu], 1u);
                }
            }
        }
        barrier_lgkm();

        // 1024-bin suffix-scan: 2 bins/thread via one ds_read_b64.
        const uint2 h = hist2[t];
        unsigned sfx[3];
        sfx[2] = 0u;
        sfx[1] = h.y;
        sfx[0] = h.y + h.x;
        hist2[t] = make_uint2(0u, 0u);     // ready for next round
        const unsigned tot = sfx[0];
        unsigned incl = tot;
        #pragma unroll
        for (int off = 1; off < 64; off <<= 1) {
            unsigned y = __shfl_down(incl, off);
            incl += (lane + off < 64) ? y : 0u;
        }
        if (lane == 0) wtot[wave] = incl;
        barrier_lgkm();
        unsigned gb = incl - tot;
        #pragma unroll
        for (int w = 0; w < NWAVE; ++w) gb += (w > wave) ? wtot[w] : 0u;

        const unsigned base = (unsigned)t * 2u;
        #pragma unroll
        for (int i = 0; i < 2; ++i) {
            unsigned S = gb + sfx[i];
            unsigned h2 = sfx[i] - sfx[i + 1];
            if (S >= need && S - h2 < need) {          // unique (t,i)
                if (round == 1 && S == need) {
                    // Entire straddle bin kept: finalize at 22-bit precision.
                    s_skip   = 1u;
                    s_prefix = ((pref << 10) | (base + (unsigned)i)) << 10;
                    s_need   = h2;                     // keepEq
                    s_sub    = h2;                     // eqCnt -> simple path
                } else {
                    s_prefix = (pref << 10) | (base + (unsigned)i);  // 22b / 32b
                    s_need   = need - (S - h2);
                    s_sub    = h2;
                }
            }
        }
        barrier_lgkm();
    }

    const unsigned thresh = s_prefix;   // exact key (or 22-bit lower bound) of cut
    const unsigned keepEq = s_need;     // # threshold-equal elements to keep
    const unsigned eqCnt  = s_sub;      // total threshold-equal elements
    const bool simple = (eqCnt == keepEq);

    // ---- Output pass straight from registers (coalesced float4 stores) ----
    if (simple) {
        #pragma unroll
        for (int j = 0; j < EPT; ++j) {
            uint4 k = kreg[j];
            float4 o;
            o.x = (k.x >= thresh) ? valOf(k.x) : 0.0f;
            o.y = (k.y >= thresh) ? valOf(k.y) : 0.0f;
            o.z = (k.z >= thresh) ? valOf(k.z) : 0.0f;
            o.w = (k.w >= thresh) ? valOf(k.w) : 0.0f;
            orow[j * NT + t] = o;
        }
    } else {
        #pragma unroll
        for (int j = 0; j < EPT; ++j) {
            uint4 k = kreg[j];
            float4 o;
            o.x = (k.x > thresh) ? valOf(k.x) : 0.0f;
            o.y = (k.y > thresh) ? valOf(k.y) : 0.0f;
            o.z = (k.z > thresh) ? valOf(k.z) : 0.0f;
            o.w = (k.w > thresh) ? valOf(k.w) : 0.0f;
            orow[j * NT + t] = o;
        }
        // ---- Rare tie path: stable (lowest-index) selection among equals ----
        #pragma unroll
        for (int j = 0; j < EPT; ++j) {
            #pragma unroll
            for (int c = 0; c < 4; ++c) {
                unsigned key = (&kreg[j].x)[c];
                if (key == thresh) {
                    unsigned slot = atomicAdd(&s_tiecnt, 1u);
                    if (slot < 64u) tiebuf[slot] = 4u * (unsigned)(j * NT + t) + (unsigned)c;
                }
            }
        }
        barrier_full();   // this row's stores must land before t0's overwrites
        if (t == 0) {
            const unsigned m = s_tiecnt;
            const float v = valOf(thresh);
            if (m <= 64u) {
                for (unsigned i = 0; i < m; ++i) {
                    unsigned idx = tiebuf[i], rank = 0;
                    for (unsigned q = 0; q < m; ++q) rank += (tiebuf[q] < idx);
                    if (rank < keepEq) out[(size_t)row * FDIM + idx] = v;
                }
            } else {
                unsigned c = 0;
                for (int i = 0; i < FDIM && c < keepEq; ++i) {
                    if (keyOf(__float_as_uint(x[(size_t)row * FDIM + i])) == thresh) {
                        out[(size_t)row * FDIM + i] = v; ++c;
                    }
                }
            }
        }
    }
}

extern "C" void kernel_launch(void* const* d_in, const int* in_sizes, int n_in,
                              void* d_out, int out_size, void* d_ws, size_t ws_size,
                              hipStream_t stream) {
    const float* x = (const float*)d_in[0];
    float* out = (float*)d_out;
    topk_mask_kernel<<<dim3(FDIM), dim3(NT), 0, stream>>>(x, out);
}